// Round 1
// baseline (1038.956 us; speedup 1.0000x reference)
//
#include <hip/hip_runtime.h>
#include <math.h>

#define NBINS 10
#define MAIN_BLOCKS 2048
#define MAIN_THREADS 256

// ws layout: [0..9] counts, [10..19] sum_conf, [20..29] sum_acc  (floats)

__global__ void ece_zero_ws(float* ws) {
    int i = threadIdx.x;
    if (i < 3 * NBINS) ws[i] = 0.0f;
}

__global__ __launch_bounds__(MAIN_THREADS) void ece_main(
        const float* __restrict__ logits,
        const int* __restrict__ labels,
        float* __restrict__ ws,
        int N) {
    __shared__ float sbin[3 * NBINS];
    const int tid = threadIdx.x;
    if (tid < 3 * NBINS) sbin[tid] = 0.0f;
    __syncthreads();

    const int lane = tid & 63;
    const int waveInBlock = tid >> 6;
    const int wavesPerBlock = MAIN_THREADS >> 6;
    const long long globalWave = (long long)blockIdx.x * wavesPerBlock + waveInBlock;
    const long long totalWaves = (long long)gridDim.x * wavesPerBlock;

    const int half = lane >> 5;    // which of the 2 rows this wave-half handles
    const int hlane = lane & 31;   // lane within the half

    const long long nPairs = ((long long)N + 1) >> 1;
    const float4* logits4 = (const float4*)logits;  // row = 25 float4 (C=100)

    for (long long p = globalWave; p < nPairs; p += totalWaves) {
        const long long row = 2 * p + half;
        const bool rowValid = (row < (long long)N);

        float m = -INFINITY;
        int midx = 0;
        if (rowValid && hlane < 25) {
            float4 v = logits4[row * 25 + hlane];
            const int e = hlane * 4;
            m = v.x; midx = e;
            if (v.y > m) { m = v.y; midx = e + 1; }
            if (v.z > m) { m = v.z; midx = e + 2; }
            if (v.w > m) { m = v.w; midx = e + 3; }
        }

        // butterfly max+argmax within the 32-lane half (first-occurrence ties)
        #pragma unroll
        for (int off = 16; off >= 1; off >>= 1) {
            float om = __shfl_xor(m, off, 32);
            int   oi = __shfl_xor(midx, off, 32);
            if (om > m || (om == m && oi < midx)) { m = om; midx = oi; }
        }

        if (rowValid && hlane == 0) {
            const float conf = expf(m);                    // log-prob -> prob
            const int b = (int)ceilf(conf * 10.0f) - 1;    // bin (i/10,(i+1)/10]
            const float acc = (midx == labels[row]) ? 1.0f : 0.0f;
            if (b >= 0 && b < NBINS) {
                atomicAdd(&sbin[b], 1.0f);
                atomicAdd(&sbin[NBINS + b], conf);
                atomicAdd(&sbin[2 * NBINS + b], acc);
            }
        }
    }

    __syncthreads();
    if (tid < 3 * NBINS) {
        const float v = sbin[tid];
        if (v != 0.0f) atomicAdd(&ws[tid], v);
    }
}

__global__ void ece_final(const float* __restrict__ ws, float* __restrict__ out, int N) {
    if (threadIdx.x == 0 && blockIdx.x == 0) {
        float ece = 0.0f;
        for (int b = 0; b < NBINS; ++b) {
            const float cnt = ws[b];
            if (cnt > 0.0f) {
                const float avg_conf = ws[NBINS + b] / cnt;
                const float avg_acc  = ws[2 * NBINS + b] / cnt;
                ece += fabsf(avg_conf - avg_acc) * (cnt / (float)N);
            }
        }
        out[0] = ece;
    }
}

extern "C" void kernel_launch(void* const* d_in, const int* in_sizes, int n_in,
                              void* d_out, int out_size, void* d_ws, size_t ws_size,
                              hipStream_t stream) {
    const float* logits = (const float*)d_in[0];
    const int*   labels = (const int*)d_in[1];
    float* out = (float*)d_out;
    float* ws  = (float*)d_ws;

    const int N = in_sizes[1];          // 2,000,000 rows (C = in_sizes[0]/N = 100)

    ece_zero_ws<<<1, 64, 0, stream>>>(ws);
    ece_main<<<MAIN_BLOCKS, MAIN_THREADS, 0, stream>>>(logits, labels, ws, N);
    ece_final<<<1, 64, 0, stream>>>(ws, out, N);
}